// Round 1
// baseline (192.338 us; speedup 1.0000x reference)
//
#include <hip/hip_runtime.h>

#define NB   32
#define NSEG 96          // 3 channels * 32 bins
#define NSUB 8           // LDS sub-histograms (one per half-wave of a 256-thread block)
#define SUBPAD 97        // pad stride to stagger bank mapping across copies

__global__ __launch_bounds__(256) void ccl_hist(
    const float4* __restrict__ pred,
    const float4* __restrict__ target,
    const float4* __restrict__ img,
    long n4,
    double* __restrict__ gdiff,
    unsigned int* __restrict__ gcnt)
{
    __shared__ float        sdiff[NSUB][SUBPAD];
    __shared__ unsigned int scnt [NSUB][SUBPAD];

    for (int i = threadIdx.x; i < NSUB * SUBPAD; i += blockDim.x) {
        (&sdiff[0][0])[i] = 0.0f;
        (&scnt [0][0])[i] = 0u;
    }
    __syncthreads();

    const int sub = threadIdx.x >> 5;   // 8 copies: halves of each of 4 waves
    long idx    = (long)blockIdx.x * blockDim.x + threadIdx.x;
    long stride = (long)gridDim.x * blockDim.x;

    for (long i = idx; i < n4; i += stride) {
        float4 xv = img[i];
        float4 pv = pred[i];
        float4 tv = target[i];
        // layout (N,C,H,W): 512*512 = 2^18 elems/channel = 2^16 float4s
        int c    = (int)((i >> 16) % 3);
        int base = c * NB;

        float xs[4] = {xv.x, xv.y, xv.z, xv.w};
        float ps[4] = {pv.x, pv.y, pv.z, pv.w};
        float ts[4] = {tv.x, tv.y, tv.z, tv.w};
#pragma unroll
        for (int k = 0; k < 4; ++k) {
            float xe = xs[k];
            // valid bin iff 0 <= x < 1; (int)(x*32) == floor(32x) exactly
            // (x*32 is exact: power-of-2 scale; edges i/32 are exact fp32)
            if (xe >= 0.0f && xe < 1.0f) {
                int b = base + (int)(xe * 32.0f);
                atomicAdd(&sdiff[sub][b], ps[k] - ts[k]);
                atomicAdd(&scnt [sub][b], 1u);
            }
        }
    }
    __syncthreads();

    // combine sub-histograms, one fp64 global atomic per segment per block
    for (int s = threadIdx.x; s < NSEG; s += blockDim.x) {
        float        d  = 0.0f;
        unsigned int cn = 0u;
#pragma unroll
        for (int u = 0; u < NSUB; ++u) { d += sdiff[u][s]; cn += scnt[u][s]; }
        if (cn > 0u) {
            atomicAdd(&gdiff[s], (double)d);
            atomicAdd(&gcnt[s], cn);
        }
    }
}

__global__ __launch_bounds__(128) void ccl_final(
    const double* __restrict__ gdiff,
    const unsigned int* __restrict__ gcnt,
    float* __restrict__ out)
{
    __shared__ double red[128];
    int t = threadIdx.x;
    double v = 0.0;
    if (t < NSEG) {
        unsigned int c = gcnt[t];
        if (c > 0u) v = fabs(gdiff[t] / (double)c);  // empty bin -> 0 (both curves 0)
    }
    red[t] = v;
    __syncthreads();
    for (int off = 64; off > 0; off >>= 1) {
        if (t < off) red[t] += red[t + off];
        __syncthreads();
    }
    if (t == 0) out[0] = (float)(red[0] / (double)NSEG);
}

extern "C" void kernel_launch(void* const* d_in, const int* in_sizes, int n_in,
                              void* d_out, int out_size, void* d_ws, size_t ws_size,
                              hipStream_t stream) {
    const float4* pred   = (const float4*)d_in[0];
    const float4* target = (const float4*)d_in[1];
    const float4* img    = (const float4*)d_in[2];
    long n4 = (long)in_sizes[0] / 4;

    double*       gdiff = (double*)d_ws;
    unsigned int* gcnt  = (unsigned int*)((char*)d_ws + NSEG * sizeof(double));

    // ws is re-poisoned to 0xAA before every launch — must zero our accumulators
    hipMemsetAsync(d_ws, 0, NSEG * (sizeof(double) + sizeof(unsigned int)), stream);

    ccl_hist<<<dim3(1024), dim3(256), 0, stream>>>(pred, target, img, n4, gdiff, gcnt);
    ccl_final<<<dim3(1), dim3(128), 0, stream>>>(gdiff, gcnt, (float*)d_out);
}